// Round 1
// baseline (269.453 us; speedup 1.0000x reference)
//
#include <hip/hip_runtime.h>

using bf16x8 = __attribute__((ext_vector_type(8))) short;
using f32x4  = __attribute__((ext_vector_type(4))) float;

#define DEVI __device__ __forceinline__

static constexpr int S_LEN = 2048, D_MODEL = 768, NH = 12, HDIM = 64;
static constexpr float SCALE = 0.125f;              // 1/sqrt(64)
static constexpr float LOG2E = 1.4426950408889634f;

DEVI unsigned short f2bf(float x) {                 // RNE f32->bf16
    unsigned u = __builtin_bit_cast(unsigned, x);
    u += 0x7fffu + ((u >> 16) & 1u);
    return (unsigned short)(u >> 16);
}

// global->LDS direct copy, 16B per lane, dest = wave-uniform base + lane*16 (m97/m104)
#define GLL16(gsrc, ldst) __builtin_amdgcn_global_load_lds( \
    (const __attribute__((address_space(1))) void*)(gsrc),  \
    (__attribute__((address_space(3))) void*)(ldst), 16, 0, 0)

// read a 16B fragment from a [rows][64 bf16] LDS tile with the st-style XOR swizzle
DEVI bf16x8 lds_frag(const unsigned short* lds, int row, int cb) {
    return *(const bf16x8*)((const char*)lds + row * 128 + (cb ^ ((row & 7) << 4)));
}

// ---------------- f32 -> bf16 bulk convert ----------------
__global__ void cvt_kernel(const float* __restrict__ src, unsigned short* __restrict__ dst, int n4) {
    int i = blockIdx.x * blockDim.x + threadIdx.x;
    if (i >= n4) return;
    float4 v = reinterpret_cast<const float4*>(src)[i];
    ushort4 o;
    o.x = f2bf(v.x); o.y = f2bf(v.y); o.z = f2bf(v.z); o.w = f2bf(v.w);
    reinterpret_cast<ushort4*>(dst)[i] = o;
}

// ---------------- RoPE cos/sin table: [S][32] ----------------
__global__ void rope_kernel(float* __restrict__ cos_t, float* __restrict__ sin_t) {
    int idx = blockIdx.x * 64 + threadIdx.x;        // 2048*32 entries
    int s = idx >> 5, f = idx & 31;
    float inv = exp2f(-(float)f * (13.287712379549449f / 32.0f)); // 10000^(-f/32)
    float ang = (float)s * inv;
    cos_t[idx] = cosf(ang);
    sin_t[idx] = sinf(ang);
}

// ---------------- shared GEMM mainloop: C[128x128] += A[128xK] * B[128xK]^T ----------------
// A: [M][K] bf16 row-major; B: [N][K] bf16 row-major (i.e. torch Linear weight layout).
DEVI void stage128x64(const unsigned short* __restrict__ g, unsigned short* lds,
                      int ldg, int row0, int k0, int wave, int lane) {
    int rl = lane >> 3;
    int cb = (lane & 7) << 4;
    #pragma unroll
    for (int i = 0; i < 4; ++i) {
        int r = wave * 32 + i * 8 + rl;
        // pre-swizzled GLOBAL source + linear LDS dest (rule #21 / m173)
        const char* src = (const char*)(g + (size_t)(row0 + r) * ldg + k0) + (cb ^ ((r & 7) << 4));
        GLL16(src, lds + (wave * 32 + i * 8) * 64);
    }
}

DEVI void gemm_core(const unsigned short* __restrict__ Ag, const unsigned short* __restrict__ Bg,
                    int m0, int n0, int K, int lda, int ldb,
                    unsigned short* As, unsigned short* Bs, f32x4 acc[4][4]) {
    int tid = threadIdx.x, wave = tid >> 6, lane = tid & 63;
    int wr = wave >> 1, wc = wave & 1, lrow = lane & 15, lk = lane >> 4;
    #pragma unroll
    for (int mi = 0; mi < 4; ++mi)
        #pragma unroll
        for (int ni = 0; ni < 4; ++ni) acc[mi][ni] = f32x4{0.f, 0.f, 0.f, 0.f};
    for (int k0 = 0; k0 < K; k0 += 64) {
        stage128x64(Ag, As, lda, m0, k0, wave, lane);
        stage128x64(Bg, Bs, ldb, n0, k0, wave, lane);
        __syncthreads();
        #pragma unroll
        for (int kk = 0; kk < 2; ++kk) {
            bf16x8 a[4], b[4];
            #pragma unroll
            for (int mi = 0; mi < 4; ++mi) a[mi] = lds_frag(As, wr * 64 + mi * 16 + lrow, kk * 64 + lk * 16);
            #pragma unroll
            for (int ni = 0; ni < 4; ++ni) b[ni] = lds_frag(Bs, wc * 64 + ni * 16 + lrow, kk * 64 + lk * 16);
            #pragma unroll
            for (int mi = 0; mi < 4; ++mi)
                #pragma unroll
                for (int ni = 0; ni < 4; ++ni)
                    acc[mi][ni] = __builtin_amdgcn_mfma_f32_16x16x32_bf16(a[mi], b[ni], acc[mi][ni], 0, 0, 0);
        }
        __syncthreads();
    }
}

// ---------------- QKV projection + RoPE + layout ----------------
// z=0: Q -> (BH,S,HD) rope'd; z=1: K -> same; z=2: V -> transposed (BH,HD,S)
__global__ __launch_bounds__(256) void qkv_kernel(
        const unsigned short* __restrict__ Xg,
        const unsigned short* __restrict__ Wqg, const unsigned short* __restrict__ Wkg,
        const unsigned short* __restrict__ Wvg,
        const float* __restrict__ cos_t, const float* __restrict__ sin_t,
        unsigned short* __restrict__ Qo, unsigned short* __restrict__ Ko,
        unsigned short* __restrict__ Vt) {
    __shared__ unsigned short As[128 * 64], Bs[128 * 64];
    int z = blockIdx.z;
    const unsigned short* Wg = (z == 0) ? Wqg : ((z == 1) ? Wkg : Wvg);
    int m0 = blockIdx.x * 128, n0 = blockIdx.y * 128;
    f32x4 acc[4][4];
    gemm_core(Xg, Wg, m0, n0, D_MODEL, D_MODEL, D_MODEL, As, Bs, acc);

    int tid = threadIdx.x, wave = tid >> 6, lane = tid & 63;
    int wr = wave >> 1, wc = wave & 1, lrow = lane & 15, lk = lane >> 4;
    int h = blockIdx.y * 2 + wc;                    // each wave's 64 cols = one head

    if (z < 2) {
        unsigned short* O = (z == 0) ? Qo : Ko;
        #pragma unroll
        for (int mi = 0; mi < 4; ++mi) {
            #pragma unroll
            for (int r = 0; r < 4; ++r) {
                int m = m0 + wr * 64 + mi * 16 + lk * 4 + r;   // m = b*S + spos
                int bb = m >> 11, spos = m & 2047;
                size_t base = ((size_t)(bb * NH + h) * S_LEN + spos) * HDIM;
                #pragma unroll
                for (int nf = 0; nf < 2; ++nf) {               // hd in [0,32): pairs with ni+2
                    int hd = nf * 16 + lrow;
                    float c = cos_t[spos * 32 + hd], sn = sin_t[spos * 32 + hd];
                    float x1 = acc[mi][nf][r], x2 = acc[mi][nf + 2][r];
                    O[base + hd]      = f2bf(x1 * c - x2 * sn);
                    O[base + hd + 32] = f2bf(x2 * c + x1 * sn);
                }
            }
        }
    } else {
        #pragma unroll
        for (int mi = 0; mi < 4; ++mi)
            #pragma unroll
            for (int r = 0; r < 4; ++r) {
                int m = m0 + wr * 64 + mi * 16 + lk * 4 + r;
                int bb = m >> 11, spos = m & 2047;
                #pragma unroll
                for (int nt = 0; nt < 4; ++nt) {
                    int hd = nt * 16 + lrow;
                    Vt[((size_t)(bb * NH + h) * HDIM + hd) * S_LEN + spos] = f2bf(acc[mi][nt][r]);
                }
            }
    }
}

// ---------------- causal flash attention ----------------
// grid (32, 48): x = q-tile (reversed: heavy first), y = b*H+h. 4 waves x 16 q-rows.
__global__ __launch_bounds__(256) void attn_kernel(
        const unsigned short* __restrict__ Q, const unsigned short* __restrict__ Kb,
        const unsigned short* __restrict__ Vt, unsigned short* __restrict__ Ctx) {
    __shared__ unsigned short Ks[64 * 64], Vs[64 * 64], Ps[4][16 * 64];
    int qt = (int)gridDim.x - 1 - (int)blockIdx.x;
    int bh = blockIdx.y;
    int tid = threadIdx.x, wave = tid >> 6, lane = tid & 63;
    int lrow = lane & 15, lk = lane >> 4;

    // Q fragments live in registers for the whole kernel
    const unsigned short* qptr = Q + ((size_t)bh * S_LEN + qt * 64 + wave * 16 + lrow) * HDIM;
    bf16x8 qf0 = *(const bf16x8*)(qptr + lk * 8);
    bf16x8 qf1 = *(const bf16x8*)(qptr + 32 + lk * 8);

    f32x4 o[4];
    float mrow[4], lsum[4];
    #pragma unroll
    for (int nt = 0; nt < 4; ++nt) o[nt] = f32x4{0.f, 0.f, 0.f, 0.f};
    #pragma unroll
    for (int r = 0; r < 4; ++r) { mrow[r] = -__builtin_inff(); lsum[r] = 0.f; }

    for (int kt = 0; kt <= qt; ++kt) {
        int kv0 = kt * 64;
        {   // stage K tile [64 keys][64 d] and V^T tile [64 d][64 keys]
            int rl = lane >> 3, cb = (lane & 7) << 4;
            #pragma unroll
            for (int i = 0; i < 2; ++i) {
                int r = wave * 16 + i * 8 + rl;
                int scb = cb ^ ((r & 7) << 4);
                const char* srck = (const char*)(Kb + ((size_t)bh * S_LEN + kv0 + r) * HDIM) + scb;
                GLL16(srck, Ks + (wave * 16 + i * 8) * 64);
                const char* srcv = (const char*)(Vt + ((size_t)bh * HDIM + r) * S_LEN + kv0) + scb;
                GLL16(srcv, Vs + (wave * 16 + i * 8) * 64);
            }
        }
        __syncthreads();

        // scores: D[q][key], q = 4*lk + r, key = nt*16 + lrow
        f32x4 sc[4];
        #pragma unroll
        for (int nt = 0; nt < 4; ++nt) sc[nt] = f32x4{0.f, 0.f, 0.f, 0.f};
        #pragma unroll
        for (int kk = 0; kk < 2; ++kk) {
            bf16x8 qf = kk ? qf1 : qf0;
            #pragma unroll
            for (int nt = 0; nt < 4; ++nt) {
                bf16x8 kf = lds_frag(Ks, nt * 16 + lrow, kk * 64 + lk * 16);
                sc[nt] = __builtin_amdgcn_mfma_f32_16x16x32_bf16(qf, kf, sc[nt], 0, 0, 0);
            }
        }

        bool diag = (kt == qt);
        #pragma unroll
        for (int r = 0; r < 4; ++r) {
            int qrel = wave * 16 + lk * 4 + r;
            float t[4];
            float mx = -__builtin_inff();
            #pragma unroll
            for (int nt = 0; nt < 4; ++nt) {
                float v = sc[nt][r] * SCALE;
                if (diag && (nt * 16 + lrow > qrel)) v = -__builtin_inff();
                t[nt] = v;
                mx = fmaxf(mx, v);
            }
            #pragma unroll
            for (int m = 1; m < 16; m <<= 1) mx = fmaxf(mx, __shfl_xor(mx, m, 64));
            float mnew = fmaxf(mrow[r], mx);
            float alpha = exp2f((mrow[r] - mnew) * LOG2E);
            mrow[r] = mnew;
            float ps = 0.f;
            int q = lk * 4 + r;
            #pragma unroll
            for (int nt = 0; nt < 4; ++nt) {
                float p = exp2f((t[nt] - mnew) * LOG2E);
                ps += p;
                *(unsigned short*)((char*)Ps[wave] + q * 128 +
                                   ((nt * 32 + lrow * 2) ^ ((q & 7) << 4))) = f2bf(p);
            }
            #pragma unroll
            for (int m = 1; m < 16; m <<= 1) ps += __shfl_xor(ps, m, 64);
            lsum[r] = lsum[r] * alpha + ps;
            #pragma unroll
            for (int nt = 0; nt < 4; ++nt) o[nt][r] *= alpha;
        }

        // PV: o[q][d] += P[q][key] * V[key][d]  (V^T staged so k=key is contiguous)
        #pragma unroll
        for (int kk = 0; kk < 2; ++kk) {
            bf16x8 pf = lds_frag(Ps[wave], lrow, kk * 64 + lk * 16);
            #pragma unroll
            for (int nt = 0; nt < 4; ++nt) {
                bf16x8 vf = lds_frag(Vs, nt * 16 + lrow, kk * 64 + lk * 16);
                o[nt] = __builtin_amdgcn_mfma_f32_16x16x32_bf16(pf, vf, o[nt], 0, 0, 0);
            }
        }
        __syncthreads();
    }

    // ctx -> (B,S,H,HD) bf16 row-major over D for out-proj
    int b = bh / NH, h = bh % NH;
    #pragma unroll
    for (int r = 0; r < 4; ++r) {
        float inv = 1.0f / lsum[r];
        int spos = qt * 64 + wave * 16 + lk * 4 + r;
        size_t base = ((size_t)(b * S_LEN + spos)) * D_MODEL + h * HDIM;
        #pragma unroll
        for (int nt = 0; nt < 4; ++nt)
            Ctx[base + nt * 16 + lrow] = f2bf(o[nt][r] * inv);
    }
}

// ---------------- output projection + bias ----------------
__global__ __launch_bounds__(256) void outproj_kernel(
        const unsigned short* __restrict__ Cg, const unsigned short* __restrict__ Wog,
        const float* __restrict__ bo, float* __restrict__ Out) {
    __shared__ unsigned short As[128 * 64], Bs[128 * 64];
    int m0 = blockIdx.x * 128, n0 = blockIdx.y * 128;
    f32x4 acc[4][4];
    gemm_core(Cg, Wog, m0, n0, D_MODEL, D_MODEL, D_MODEL, As, Bs, acc);

    int tid = threadIdx.x, wave = tid >> 6, lane = tid & 63;
    int wr = wave >> 1, wc = wave & 1, lrow = lane & 15, lk = lane >> 4;
    #pragma unroll
    for (int mi = 0; mi < 4; ++mi)
        #pragma unroll
        for (int r = 0; r < 4; ++r) {
            int m = m0 + wr * 64 + mi * 16 + lk * 4 + r;
            #pragma unroll
            for (int nt = 0; nt < 4; ++nt) {
                int n = n0 + wc * 64 + nt * 16 + lrow;
                Out[(size_t)m * D_MODEL + n] = acc[mi][nt][r] + bo[n];
            }
        }
}

extern "C" void kernel_launch(void* const* d_in, const int* in_sizes, int n_in,
                              void* d_out, int out_size, void* d_ws, size_t ws_size,
                              hipStream_t stream) {
    const float* embeds = (const float*)d_in[0];
    const float* Wq = (const float*)d_in[1];
    const float* Wk = (const float*)d_in[2];
    const float* Wv = (const float*)d_in[3];
    const float* Wo = (const float*)d_in[4];
    const float* bo = (const float*)d_in[5];
    float* out = (float*)d_out;

    const size_t NE = (size_t)4 * 2048 * 768;   // 6291456 elements
    const size_t NW = (size_t)768 * 768;        // 589824

    unsigned short* ws     = (unsigned short*)d_ws;
    unsigned short* emb_bf = ws;                // dead after qkv -> reused as ctx
    unsigned short* wq_bf  = emb_bf + NE;
    unsigned short* wk_bf  = wq_bf + NW;
    unsigned short* wv_bf  = wk_bf + NW;
    unsigned short* wo_bf  = wv_bf + NW;
    unsigned short* qb     = wo_bf + NW;
    unsigned short* kb     = qb + NE;
    unsigned short* vt     = kb + NE;
    float* cos_t = (float*)(vt + NE);
    float* sin_t = cos_t + 2048 * 32;
    unsigned short* ctx = emb_bf;               // alias (emb consumed before attn writes)
    // total ws use: (4*NE + 4*NW)*2 + 2048*32*2*4 B  ~= 56 MB

    cvt_kernel<<<dim3((unsigned)((NE / 4 + 255) / 256)), 256, 0, stream>>>(embeds, emb_bf, (int)(NE / 4));
    cvt_kernel<<<dim3((unsigned)((NW / 4 + 255) / 256)), 256, 0, stream>>>(Wq, wq_bf, (int)(NW / 4));
    cvt_kernel<<<dim3((unsigned)((NW / 4 + 255) / 256)), 256, 0, stream>>>(Wk, wk_bf, (int)(NW / 4));
    cvt_kernel<<<dim3((unsigned)((NW / 4 + 255) / 256)), 256, 0, stream>>>(Wv, wv_bf, (int)(NW / 4));
    cvt_kernel<<<dim3((unsigned)((NW / 4 + 255) / 256)), 256, 0, stream>>>(Wo, wo_bf, (int)(NW / 4));
    rope_kernel<<<dim3(1024), 64, 0, stream>>>(cos_t, sin_t);

    qkv_kernel<<<dim3(64, 6, 3), 256, 0, stream>>>(emb_bf, wq_bf, wk_bf, wv_bf,
                                                   cos_t, sin_t, qb, kb, vt);
    attn_kernel<<<dim3(32, 48), 256, 0, stream>>>(qb, kb, vt, ctx);
    outproj_kernel<<<dim3(64, 6), 256, 0, stream>>>(ctx, wo_bf, bo, out);
}